// Round 1
// baseline (1314.831 us; speedup 1.0000x reference)
//
#include <hip/hip_runtime.h>

#define N_USERS 100000
#define N_ITEMS 50000
#define N_NODES 150000
#define NNZ_C   6000000
#define LAT     64
#define BATCH   2048

// ---------------- utility ----------------
__global__ __launch_bounds__(256) void k_zero(int* p, int n) {
    int i = blockIdx.x * blockDim.x + threadIdx.x;
    int stride = gridDim.x * blockDim.x;
    for (; i < n; i += stride) p[i] = 0;
}

// ---------------- CSR build ----------------
__global__ __launch_bounds__(256) void k_hist(const int* __restrict__ row,
                                              int* __restrict__ cnt, int n) {
    int i = blockIdx.x * blockDim.x + threadIdx.x;
    int stride = gridDim.x * blockDim.x;
    for (; i < n; i += stride) atomicAdd(&cnt[row[i]], 1);
}

// block b sums cnt[b*1024 .. b*1024+1023] -> partials[b]
__global__ __launch_bounds__(256) void k_blocksum(const int* __restrict__ cnt,
                                                  int* __restrict__ partials) {
    __shared__ int s[256];
    int base = blockIdx.x * 1024;
    int t = threadIdx.x;
    int sum = 0;
    for (int k = 0; k < 4; ++k) {
        int idx = base + t + k * 256;
        if (idx < N_NODES) sum += cnt[idx];
    }
    s[t] = sum; __syncthreads();
    for (int off = 128; off > 0; off >>= 1) {
        if (t < off) s[t] += s[t + off];
        __syncthreads();
    }
    if (t == 0) partials[blockIdx.x] = s[0];
}

// single block: exclusive scan of partials (nb <= 256); total -> row_ptr[N_NODES]
__global__ __launch_bounds__(256) void k_scan_partials(const int* __restrict__ partials,
                                                       int* __restrict__ scanned,
                                                       int* __restrict__ row_ptr, int nb) {
    __shared__ int s[256];
    int t = threadIdx.x;
    int v = (t < nb) ? partials[t] : 0;
    s[t] = v; __syncthreads();
    for (int off = 1; off < 256; off <<= 1) {
        int x = 0;
        if (t >= off) x = s[t - off];
        __syncthreads();
        s[t] += x;
        __syncthreads();
    }
    scanned[t] = s[t] - v;          // exclusive
    if (t == 255) row_ptr[N_NODES] = s[255];
}

// block b: exclusive scan within its 1024-chunk; cnt may alias cursor (each
// element is read then written by the same thread) — no __restrict__ here.
__global__ __launch_bounds__(256) void k_scan_chunk(const int* cnt,
                                                    const int* __restrict__ scanned,
                                                    int* row_ptr, int* cursor) {
    __shared__ int s[256];
    int b = blockIdx.x, t = threadIdx.x;
    int base = b * 1024 + t * 4;
    int v[4];
    int sum = 0;
    for (int k = 0; k < 4; ++k) {
        int idx = base + k;
        v[k] = (idx < N_NODES) ? cnt[idx] : 0;
        sum += v[k];
    }
    int own = sum;
    s[t] = sum; __syncthreads();
    for (int off = 1; off < 256; off <<= 1) {
        int x = 0;
        if (t >= off) x = s[t - off];
        __syncthreads();
        s[t] += x;
        __syncthreads();
    }
    int excl = scanned[b] + s[t] - own;
    for (int k = 0; k < 4; ++k) {
        int idx = base + k;
        if (idx < N_NODES) { row_ptr[idx] = excl; cursor[idx] = excl; }
        excl += v[k];
    }
}

__global__ __launch_bounds__(256) void k_scatter(const int* __restrict__ row,
                                                 const int* __restrict__ col,
                                                 const float* __restrict__ vals,
                                                 int* cursor, int2* __restrict__ edges, int n) {
    int i = blockIdx.x * blockDim.x + threadIdx.x;
    int stride = gridDim.x * blockDim.x;
    for (; i < n; i += stride) {
        int r = row[i];
        int pos = atomicAdd(&cursor[r], 1);
        edges[pos] = make_int2(col[i], __float_as_int(vals[i]));
    }
}

// ---------------- dense pieces ----------------
__global__ __launch_bounds__(256) void k_concat(const float4* __restrict__ u,
                                                const float4* __restrict__ it,
                                                float4* __restrict__ dst) {
    int i = blockIdx.x * blockDim.x + threadIdx.x;
    int stride = gridDim.x * blockDim.x;
    const int nu = N_USERS * (LAT / 4), ni = N_ITEMS * (LAT / 4);
    for (; i < nu + ni; i += stride)
        dst[i] = (i < nu) ? u[i] : it[i - nu];
}

// wave-per-row CSR SpMM: lane = latent dim
__global__ __launch_bounds__(256) void k_spmm(const int* __restrict__ row_ptr,
                                              const int2* __restrict__ edges,
                                              const float* __restrict__ x,
                                              float* __restrict__ y) {
    int gid  = blockIdx.x * blockDim.x + threadIdx.x;
    int wave = gid >> 6;
    int lane = threadIdx.x & 63;
    if (wave >= N_NODES) return;
    int beg = row_ptr[wave], end = row_ptr[wave + 1];
    float a0 = 0.f, a1 = 0.f, a2 = 0.f, a3 = 0.f;
    int j = beg;
    for (; j + 4 <= end; j += 4) {
        int2 e0 = edges[j], e1 = edges[j + 1], e2 = edges[j + 2], e3 = edges[j + 3];
        a0 += __int_as_float(e0.y) * x[e0.x * LAT + lane];
        a1 += __int_as_float(e1.y) * x[e1.x * LAT + lane];
        a2 += __int_as_float(e2.y) * x[e2.x * LAT + lane];
        a3 += __int_as_float(e3.y) * x[e3.x * LAT + lane];
    }
    for (; j < end; ++j) {
        int2 e = edges[j];
        a0 += __int_as_float(e.y) * x[e.x * LAT + lane];
    }
    y[wave * LAT + lane] = (a0 + a1) + (a2 + a3);
}

// accumulate layer output at the 4096 selected nodes only
__global__ __launch_bounds__(256) void k_accsel(const float* __restrict__ emb,
                                                const int* __restrict__ users,
                                                const int* __restrict__ items,
                                                float* acc, int initFlag) {
    int gid  = blockIdx.x * blockDim.x + threadIdx.x;
    int w    = gid >> 6;
    int lane = threadIdx.x & 63;
    if (w >= 2 * BATCH) return;
    int node = (w < BATCH) ? users[w] : (N_USERS + items[w - BATCH]);
    float v = emb[node * LAT + lane];
    if (initFlag) acc[w * LAT + lane] = v;
    else          acc[w * LAT + lane] += v;
}

__global__ __launch_bounds__(256) void k_dot(const float* __restrict__ acc,
                                             float* __restrict__ out) {
    int gid  = blockIdx.x * blockDim.x + threadIdx.x;
    int w    = gid >> 6;
    int lane = threadIdx.x & 63;
    if (w >= BATCH) return;
    float p = acc[w * LAT + lane] * acc[(BATCH + w) * LAT + lane];
    for (int off = 32; off > 0; off >>= 1) p += __shfl_down(p, off, 64);
    if (lane == 0) out[w] = p * (1.0f / 16.0f);   // (/4)·(/4) folded into dot
}

// ---------------- launch ----------------
extern "C" void kernel_launch(void* const* d_in, const int* in_sizes, int n_in,
                              void* d_out, int out_size, void* d_ws, size_t ws_size,
                              hipStream_t stream) {
    const int*   row_idx  = (const int*)d_in[0];
    const int*   col_idx  = (const int*)d_in[1];
    const float* vals     = (const float*)d_in[2];
    const float* user_emb = (const float*)d_in[3];
    const float* item_emb = (const float*)d_in[4];
    const int*   users    = (const int*)d_in[5];
    const int*   items    = (const int*)d_in[6];
    float*       out      = (float*)d_out;

    char* ws = (char*)d_ws;
    size_t off = 0;
    auto alloc = [&](size_t bytes) -> void* {
        void* p = ws + off;
        off = (off + bytes + 255) & ~(size_t)255;
        return p;
    };
    int*   row_ptr  = (int*)alloc((N_NODES + 1) * sizeof(int));
    int*   cursor   = (int*)alloc((size_t)N_NODES * sizeof(int));   // doubles as cnt
    int*   partials = (int*)alloc(256 * sizeof(int));
    int*   scanned  = (int*)alloc(256 * sizeof(int));
    int2*  edges    = (int2*)alloc((size_t)NNZ_C * sizeof(int2));
    float* embA     = (float*)alloc((size_t)N_NODES * LAT * sizeof(float));
    float* embB     = (float*)alloc((size_t)N_NODES * LAT * sizeof(float));
    float* acc      = (float*)alloc((size_t)2 * BATCH * LAT * sizeof(float));

    const int nb_chunks = (N_NODES + 1023) / 1024;   // 147

    k_zero<<<1024, 256, 0, stream>>>(cursor, N_NODES);
    k_hist<<<2048, 256, 0, stream>>>(row_idx, cursor, NNZ_C);
    k_blocksum<<<nb_chunks, 256, 0, stream>>>(cursor, partials);
    k_scan_partials<<<1, 256, 0, stream>>>(partials, scanned, row_ptr, nb_chunks);
    k_scan_chunk<<<nb_chunks, 256, 0, stream>>>(cursor, scanned, row_ptr, cursor);
    k_scatter<<<2048, 256, 0, stream>>>(row_idx, col_idx, vals, cursor, edges, NNZ_C);

    k_concat<<<2048, 256, 0, stream>>>((const float4*)user_emb,
                                       (const float4*)item_emb, (float4*)embA);
    k_accsel<<<(2 * BATCH * 64) / 256, 256, 0, stream>>>(embA, users, items, acc, 1);

    float* cur = embA;
    float* nxt = embB;
    for (int l = 0; l < 3; ++l) {
        k_spmm<<<(N_NODES + 3) / 4, 256, 0, stream>>>(row_ptr, edges, cur, nxt);
        k_accsel<<<(2 * BATCH * 64) / 256, 256, 0, stream>>>(nxt, users, items, acc, 0);
        float* t = cur; cur = nxt; nxt = t;
    }
    k_dot<<<(BATCH * 64) / 256, 256, 0, stream>>>(acc, out);
}